// Round 3
// baseline (3510.560 us; speedup 1.0000x reference)
//
#include <hip/hip_runtime.h>
#include <hip/hip_bf16.h>

// RecurrentEntityNetwork on MI355X. S=128, B=1024, DOBJ=37, QD=11, D=256, M=20.
// Dual-dtype (runtime probe on prelu_a bits): inputs either bf16 or f32.
// phase1: jv = relu(relu(MI@C^T+Cb)@V^T+Vb)@J2^T -> ws (bf16, 64MB)
// recur : persistent 256 WGs, 2 batches/WG per pass, 2 passes; 63.3KB LDS.

#define S_LEN 128
#define BSZ   1024
#define DOBJ  37
#define QD    11

typedef float f32x4 __attribute__((ext_vector_type(4)));
typedef short bf16x8 __attribute__((ext_vector_type(8)));

#define MFMA16(a, b, c) __builtin_amdgcn_mfma_f32_16x16x32_bf16((a), (b), (c), 0, 0, 0)

__device__ __forceinline__ float b2f(short h) {
    union { unsigned u; float f; } c; c.u = ((unsigned)(unsigned short)h) << 16; return c.f;
}
__device__ __forceinline__ short f2b(float x) {   // f32 -> bf16 RNE
    union { float f; unsigned u; } c; c.f = x;
    return (short)((c.u + 0x7FFFu + ((c.u >> 16) & 1u)) >> 16);
}
__device__ __forceinline__ float ld1(const void* p, int i, bool f32) {
    return f32 ? ((const float*)p)[i] : b2f(((const short*)p)[i]);
}
__device__ __forceinline__ bf16x8 ld8(const void* p, int i, bool f32) {  // i: 8-elem aligned
    if (!f32) return *(const bf16x8*)((const short*)p + i);
    const float* q = (const float*)p + i;
    bf16x8 r;
    #pragma unroll
    for (int e = 0; e < 8; ++e) r[e] = f2b(q[e]);
    return r;
}

// ---------------------------------------------------------------------------
// Phase 1: jv for all (s,b). 64 rows/WG, grid 2048.
// ---------------------------------------------------------------------------
__global__ __launch_bounds__(256, 2) void renet_phase1(
    const void* __restrict__ MI, const void* __restrict__ Cw, const void* __restrict__ Cb,
    const void* __restrict__ Vw, const void* __restrict__ Vb, const void* __restrict__ Jw,
    const void* __restrict__ PA, short* __restrict__ jv_out)
{
    const bool F32 = (*(const unsigned*)PA == 0x3F800000u);
    __shared__ __align__(16) short A[64 * 264];
    __shared__ __align__(16) float MIL[64 * 40];
    __shared__ float VBL[256];

    const int t = threadIdx.x, r0 = blockIdx.x * 64;
    const int wv = t >> 6, lane = t & 63, lr = lane & 15, quad = lane >> 4;

    VBL[t] = ld1(Vb, t, F32);
    for (int c = 0; c < 10; ++c) {
        int idx = c * 256 + t;
        if (idx < 64 * 37) { int i = idx / 37, k = idx - i * 37; MIL[i * 40 + k] = ld1(MI, (r0 + i) * 37 + k, F32); }
    }
    __syncthreads();

    {   // mi = relu(MI @ Cw^T + Cb), column t
        float cw[DOBJ];
        #pragma unroll
        for (int k = 0; k < DOBJ; ++k) cw[k] = ld1(Cw, t * DOBJ + k, F32);
        float cb = ld1(Cb, t, F32);
        for (int i = 0; i < 64; ++i) {
            float a = cb;
            #pragma unroll
            for (int k = 0; k < DOBJ; ++k) a += MIL[i * 40 + k] * cw[k];
            A[i * 264 + t] = f2b(fmaxf(a, 0.f));
        }
    }
    __syncthreads();

    const f32x4 Z4 = {0.f, 0.f, 0.f, 0.f};
    f32x4 acc[4][4];

    // v = mi @ Vw^T
    #pragma unroll
    for (int rt = 0; rt < 4; ++rt)
        #pragma unroll
        for (int nt = 0; nt < 4; ++nt) acc[rt][nt] = Z4;
    #pragma unroll
    for (int kt = 0; kt < 8; ++kt) {
        bf16x8 a[4];
        #pragma unroll
        for (int rt = 0; rt < 4; ++rt)
            a[rt] = *(const bf16x8*)&A[(rt * 16 + lr) * 264 + kt * 32 + quad * 8];
        #pragma unroll
        for (int nt = 0; nt < 4; ++nt) {
            int n = wv * 64 + nt * 16 + lr;
            bf16x8 b = ld8(Vw, n * 256 + kt * 32 + quad * 8, F32);
            #pragma unroll
            for (int rt = 0; rt < 4; ++rt) acc[rt][nt] = MFMA16(a[rt], b, acc[rt][nt]);
        }
    }
    __syncthreads();
    #pragma unroll
    for (int nt = 0; nt < 4; ++nt) {
        int n = wv * 64 + nt * 16 + lr;
        float vb = VBL[n];
        #pragma unroll
        for (int rt = 0; rt < 4; ++rt)
            #pragma unroll
            for (int r = 0; r < 4; ++r)
                A[(rt * 16 + quad * 4 + r) * 264 + n] = f2b(fmaxf(acc[rt][nt][r] + vb, 0.f));
    }
    __syncthreads();

    // jv = relu_v @ J2^T (J2 = Jw[:,256:512])
    #pragma unroll
    for (int rt = 0; rt < 4; ++rt)
        #pragma unroll
        for (int nt = 0; nt < 4; ++nt) acc[rt][nt] = Z4;
    #pragma unroll
    for (int kt = 0; kt < 8; ++kt) {
        bf16x8 a[4];
        #pragma unroll
        for (int rt = 0; rt < 4; ++rt)
            a[rt] = *(const bf16x8*)&A[(rt * 16 + lr) * 264 + kt * 32 + quad * 8];
        #pragma unroll
        for (int nt = 0; nt < 4; ++nt) {
            int n = wv * 64 + nt * 16 + lr;
            bf16x8 b = ld8(Jw, n * 768 + 256 + kt * 32 + quad * 8, F32);
            #pragma unroll
            for (int rt = 0; rt < 4; ++rt) acc[rt][nt] = MFMA16(a[rt], b, acc[rt][nt]);
        }
    }
    __syncthreads();
    #pragma unroll
    for (int nt = 0; nt < 4; ++nt) {
        int n = wv * 64 + nt * 16 + lr;
        #pragma unroll
        for (int rt = 0; rt < 4; ++rt)
            #pragma unroll
            for (int r = 0; r < 4; ++r)
                A[(rt * 16 + quad * 4 + r) * 264 + n] = f2b(acc[rt][nt][r]);
    }
    __syncthreads();
    for (int c = 0; c < 16; ++c) {
        int idx = c * 1024 + t * 4;
        int i = idx >> 8, k = idx & 255;
        *(ushort4*)&jv_out[(r0 + i) * 256 + k] = *(const ushort4*)&A[i * 264 + k];
    }
}

// ---------------------------------------------------------------------------
// Recurrence + head. grid 256 x 256 thr. 2 batches/WG per pass, 2 passes.
// LDS 63.3KB. A1 rows 0..39 mem (bi*20+m), 40..59 keys.
// ---------------------------------------------------------------------------
__global__ __launch_bounds__(256, 1) void renet_recur(
    const void* __restrict__ MI, const short* __restrict__ jv,
    const void* __restrict__ Qin, const void* __restrict__ Qw, const void* __restrict__ Qb,
    const void* __restrict__ Uw, const void* __restrict__ Ub,
    const void* __restrict__ Jw, const void* __restrict__ Jb,
    const void* __restrict__ Ww, const void* __restrict__ Wb,
    const void* __restrict__ Hw, const void* __restrict__ Hb,
    const void* __restrict__ PA, const void* __restrict__ Cw, const void* __restrict__ Cb,
    const void* __restrict__ Emb, void* __restrict__ Out)
{
    const bool F32 = (*(const unsigned*)PA == 0x3F800000u);
    __shared__ __align__(16) short A1[60 * 264];   // 31680
    __shared__ __align__(16) short STG[40 * 264];  // 21120: rows 0..15 = sent B-op early-step, then relu_u restage; tail scratch
    __shared__ __align__(16) short JWL[20 * 256];  // 10240 (persistent)
    __shared__ __align__(16) short JVB[2 * 256];   // 1024
    __shared__ float GB[60 * 2];                   // 480
    __shared__ float RS[40];                       // 160
    __shared__ __align__(4) short MIL[2 * 40];     // 160   => total 64,864 B

    const int t = threadIdx.x;
    const int wv = t >> 6, lane = t & 63, lr = lane & 15, quad = lane >> 4;
    const float pa = ld1(PA, 0, F32);
    const f32x4 Z4 = {0.f, 0.f, 0.f, 0.f};
    const int rb0 = 0, rb1 = 16, rb2 = 24;

    // persistent per-thread constants
    float cw[DOBJ];
    #pragma unroll
    for (int k = 0; k < DOBJ; ++k) cw[k] = ld1(Cw, t * DOBJ + k, F32);
    const float cb = ld1(Cb, t, F32);
    float qw[QD];
    #pragma unroll
    for (int k = 0; k < QD; ++k) qw[k] = ld1(Qw, t * QD + k, F32);
    const float qb = ld1(Qb, t, F32);
    const float hb = ld1(Hb, t, F32);
    const int kk = (t & 127) * 2;
    const float bj0 = ld1(Jb, kk, F32), bj1 = ld1(Jb, kk + 1, F32);
    float ub[4];
    #pragma unroll
    for (int nt = 0; nt < 4; ++nt) ub[nt] = ld1(Ub, wv * 64 + nt * 16 + lr, F32);

    bf16x8 uf[8][4], jf[8][4];
    #pragma unroll
    for (int kt = 0; kt < 8; ++kt)
        #pragma unroll
        for (int nt = 0; nt < 4; ++nt) {
            int nn = wv * 64 + nt * 16 + lr;
            uf[kt][nt] = ld8(Uw, nn * 256 + kt * 32 + quad * 8, F32);
            jf[kt][nt] = ld8(Jw, nn * 768 + kt * 32 + quad * 8, F32);
        }

    // keys -> A1 rows 40..59
    for (int c = 0; c < 21; ++c) {
        int idx = c * 256 + t;
        if (idx < 20 * 264) {
            int row = idx / 264, k = idx - row * 264;
            A1[(40 + row) * 264 + k] = (k < 256) ? f2b(ld1(Emb, row * 256 + k, F32)) : (short)0;
        }
    }
    __syncthreads();

    // jw = relu(Emb@Ww^T+Wb) @ J3^T  (once; WKS f32 in STG)
    {
        float* WKS = (float*)STG;
        float wacc[20];
        #pragma unroll
        for (int m = 0; m < 20; ++m) wacc[m] = 0.f;
        for (int c = 0; c < 32; ++c) {
            bf16x8 w8 = ld8(Ww, t * 256 + c * 8, F32);
            float wf[8];
            #pragma unroll
            for (int e = 0; e < 8; ++e) wf[e] = b2f(w8[e]);
            #pragma unroll
            for (int m = 0; m < 20; ++m) {
                bf16x8 e8 = *(const bf16x8*)&A1[(40 + m) * 264 + c * 8];
                float s = 0.f;
                #pragma unroll
                for (int e = 0; e < 8; ++e) s += b2f(e8[e]) * wf[e];
                wacc[m] += s;
            }
        }
        float wb = ld1(Wb, t, F32);
        #pragma unroll
        for (int m = 0; m < 20; ++m) WKS[m * 256 + t] = fmaxf(wacc[m] + wb, 0.f);
        __syncthreads();
        float jacc[20];
        #pragma unroll
        for (int m = 0; m < 20; ++m) jacc[m] = 0.f;
        for (int c = 0; c < 32; ++c) {
            bf16x8 j8 = ld8(Jw, t * 768 + 512 + c * 8, F32);
            float jfv[8];
            #pragma unroll
            for (int e = 0; e < 8; ++e) jfv[e] = b2f(j8[e]);
            #pragma unroll
            for (int m = 0; m < 20; ++m) {
                float4 w0 = *(const float4*)&WKS[m * 256 + c * 8];
                float4 w1 = *(const float4*)&WKS[m * 256 + c * 8 + 4];
                jacc[m] += w0.x * jfv[0] + w0.y * jfv[1] + w0.z * jfv[2] + w0.w * jfv[3]
                         + w1.x * jfv[4] + w1.y * jfv[5] + w1.z * jfv[6] + w1.w * jfv[7];
            }
        }
        __syncthreads();
        #pragma unroll
        for (int m = 0; m < 20; ++m) JWL[m * 256 + t] = f2b(jacc[m]);
    }
    __syncthreads();

    for (int p = 0; p < 2; ++p) {
        const int bq0 = blockIdx.x * 4 + p * 2;
        // (re)init mem rows 0..39 from key rows
        for (int c = 0; c < 42; ++c) {
            int idx = c * 256 + t;
            if (idx < 40 * 264) {
                int row = idx / 264, k = idx - row * 264;
                A1[idx] = (k < 256) ? A1[(40 + row % 20) * 264 + k] : (short)0;
            }
        }
        __syncthreads();

        for (int s = 0; s < S_LEN; ++s) {
            // ---- stage MI row, jv row (+Jb), zero RS
            if (t < 74) {
                int bi = t / 37, k = t - bi * 37;
                MIL[bi * 40 + k] = f2b(ld1(MI, ((s * BSZ) + bq0 + bi) * 37 + k, F32));
            }
            {
                int bi = t >> 7, k = kk;
                short2 jvv = *(const short2*)&jv[(s * BSZ + bq0 + bi) * 256 + k];
                JVB[bi * 256 + k]     = f2b(b2f(jvv.x) + bj0);
                JVB[bi * 256 + k + 1] = f2b(b2f(jvv.y) + bj1);
            }
            if (t < 40) RS[t] = 0.f;
            __syncthreads();                                   // A

            // ---- sent rows 0..1 of STG (bf16)
            {
                float s0 = cb, s1 = cb;
                #pragma unroll
                for (int k = 0; k < DOBJ; ++k) {
                    s0 += b2f(MIL[k]) * cw[k];
                    s1 += b2f(MIL[40 + k]) * cw[k];
                }
                STG[t] = f2b(fmaxf(s0, 0.f));
                STG[264 + t] = f2b(fmaxf(s1, 0.f));
            }
            __syncthreads();                                   // B

            // ---- gate MFMA: wave wv owns rows base..base+15 of [mem;keys]
            {
                const int gb4[4] = {0, 16, 32, 44};
                const int base = gb4[wv];
                f32x4 ag = Z4;
                #pragma unroll
                for (int kt = 0; kt < 8; ++kt) {
                    bf16x8 a = *(const bf16x8*)&A1[(base + lr) * 264 + kt * 32 + quad * 8];
                    bf16x8 b = *(const bf16x8*)&STG[lr * 264 + kt * 32 + quad * 8];
                    ag = MFMA16(a, b, ag);
                }
                if (lr < 2) {
                    #pragma unroll
                    for (int r = 0; r < 4; ++r) GB[(base + quad * 4 + r) * 2 + lr] = ag[r];
                }
            }

            // ---- GEMM1: u = mem @ Uw^T  (row tiles 0-15,16-31,24-39)
            f32x4 acc[3][4];
            #pragma unroll
            for (int rt = 0; rt < 3; ++rt)
                #pragma unroll
                for (int nt = 0; nt < 4; ++nt) acc[rt][nt] = Z4;
            #pragma unroll
            for (int kt = 0; kt < 8; ++kt) {
                bf16x8 a0 = *(const bf16x8*)&A1[(rb0 + lr) * 264 + kt * 32 + quad * 8];
                bf16x8 a1 = *(const bf16x8*)&A1[(rb1 + lr) * 264 + kt * 32 + quad * 8];
                bf16x8 a2 = *(const bf16x8*)&A1[(rb2 + lr) * 264 + kt * 32 + quad * 8];
                #pragma unroll
                for (int nt = 0; nt < 4; ++nt) {
                    acc[0][nt] = MFMA16(a0, uf[kt][nt], acc[0][nt]);
                    acc[1][nt] = MFMA16(a1, uf[kt][nt], acc[1][nt]);
                    acc[2][nt] = MFMA16(a2, uf[kt][nt], acc[2][nt]);
                }
            }
            __syncthreads();                                   // B2 (sent reads done)

            // ---- restage relu(u+Ub) into STG rows 0..39
            #pragma unroll
            for (int rt = 0; rt < 3; ++rt) {
                int base = (rt == 0) ? rb0 : (rt == 1) ? rb1 : rb2;
                #pragma unroll
                for (int nt = 0; nt < 4; ++nt) {
                    int n = wv * 64 + nt * 16 + lr;
                    #pragma unroll
                    for (int r = 0; r < 4; ++r)
                        STG[(base + quad * 4 + r) * 264 + n] = f2b(fmaxf(acc[rt][nt][r] + ub[nt], 0.f));
                }
            }
            __syncthreads();                                   // C

            // ---- GEMM2: jU = relu_u @ J1^T
            f32x4 acc2[3][4];
            #pragma unroll
            for (int rt = 0; rt < 3; ++rt)
                #pragma unroll
                for (int nt = 0; nt < 4; ++nt) acc2[rt][nt] = Z4;
            #pragma unroll
            for (int kt = 0; kt < 8; ++kt) {
                bf16x8 a0 = *(const bf16x8*)&STG[(rb0 + lr) * 264 + kt * 32 + quad * 8];
                bf16x8 a1 = *(const bf16x8*)&STG[(rb1 + lr) * 264 + kt * 32 + quad * 8];
                bf16x8 a2 = *(const bf16x8*)&STG[(rb2 + lr) * 264 + kt * 32 + quad * 8];
                #pragma unroll
                for (int nt = 0; nt < 4; ++nt) {
                    acc2[0][nt] = MFMA16(a0, jf[kt][nt], acc2[0][nt]);
                    acc2[1][nt] = MFMA16(a1, jf[kt][nt], acc2[1][nt]);
                    acc2[2][nt] = MFMA16(a2, jf[kt][nt], acc2[2][nt]);
                }
            }

            // ---- epilogue pass 1: j -> cand -> upd, row sumsq (dup tile rows guarded at atomic)
            #pragma unroll
            for (int rt = 0; rt < 3; ++rt) {
                int base = (rt == 0) ? rb0 : (rt == 1) ? rb1 : rb2;
                #pragma unroll
                for (int r = 0; r < 4; ++r) {
                    int row = base + quad * 4 + r;
                    int bi = (row >= 20) ? 1 : 0;
                    int m = row - bi * 20;
                    float gp = GB[row * 2 + bi] + GB[(40 + m) * 2 + bi];
                    float gate = 1.f / (1.f + __expf(-gp));
                    float ss = 0.f;
                    #pragma unroll
                    for (int nt = 0; nt < 4; ++nt) {
                        int n = wv * 64 + nt * 16 + lr;
                        float j = acc2[rt][nt][r] + b2f(JVB[bi * 256 + n]) + b2f(JWL[m * 256 + n]);
                        float cand = j > 0.f ? j : pa * j;
                        float u = b2f(A1[row * 264 + n]) + gate * cand;
                        acc2[rt][nt][r] = u;
                        ss += u * u;
                    }
                    ss += __shfl_xor(ss, 1);
                    ss += __shfl_xor(ss, 2);
                    ss += __shfl_xor(ss, 4);
                    ss += __shfl_xor(ss, 8);
                    if (lr == 0 && (rt < 2 || quad >= 2)) atomicAdd(&RS[row], ss);
                }
            }
            __syncthreads();                                   // F

            // ---- pass 2: normalize, write back (dup rows write identical bits)
            #pragma unroll
            for (int rt = 0; rt < 3; ++rt) {
                int base = (rt == 0) ? rb0 : (rt == 1) ? rb1 : rb2;
                #pragma unroll
                for (int r = 0; r < 4; ++r) {
                    int row = base + quad * 4 + r;
                    float sc = 1.f / (sqrtf(RS[row]) + 1e-12f);
                    #pragma unroll
                    for (int nt = 0; nt < 4; ++nt) {
                        int n = wv * 64 + nt * 16 + lr;
                        A1[row * 264 + n] = f2b(acc2[rt][nt][r] * sc);
                    }
                }
            }
            __syncthreads();                                   // G
        }

        // ---------------- attention + output head (scratch in STG) ----------------
        float* SF = (float*)STG;   // QF[0..511] HC[512..1535] EN[1536..1575] AT[1576..1615]
        #pragma unroll
        for (int bi = 0; bi < 2; ++bi) {
            float a = qb;
            #pragma unroll
            for (int k = 0; k < QD; ++k) a += ld1(Qin, (bq0 + bi) * QD + k, F32) * qw[k];
            SF[bi * 256 + t] = fmaxf(a, 0.f);
        }
        __syncthreads();
        if (t < 40) {
            int bi = t / 20;
            float e = 0.f;
            for (int c = 0; c < 32; ++c) {
                bf16x8 mv = *(const bf16x8*)&A1[t * 264 + c * 8];
                #pragma unroll
                for (int e8 = 0; e8 < 8; ++e8) e += b2f(mv[e8]) * SF[bi * 256 + c * 8 + e8];
            }
            SF[1536 + t] = e;
        }
        __syncthreads();
        if (t < 2) {
            float mx = -1e30f;
            for (int m = 0; m < 20; ++m) mx = fmaxf(mx, SF[1536 + t * 20 + m]);
            float sm = 0.f, ex[20];
            for (int m = 0; m < 20; ++m) { ex[m] = __expf(SF[1536 + t * 20 + m] - mx); sm += ex[m]; }
            float inv = 1.f / sm;
            for (int m = 0; m < 20; ++m) SF[1576 + t * 20 + m] = ex[m] * inv;
        }
        __syncthreads();
        #pragma unroll
        for (int bi = 0; bi < 2; ++bi) {
            float a = 0.f;
            for (int m = 0; m < 20; ++m)
                a += SF[1576 + bi * 20 + m] * b2f(A1[(bi * 20 + m) * 264 + t]);
            SF[512 + bi * 512 + 256 + t] = a;
            SF[512 + bi * 512 + t] = SF[bi * 256 + t];
        }
        __syncthreads();
        #pragma unroll
        for (int bi = 0; bi < 2; ++bi) {
            float o = hb;
            for (int c = 0; c < 64; ++c) {
                bf16x8 hv = ld8(Hw, t * 512 + c * 8, F32);
                #pragma unroll
                for (int e8 = 0; e8 < 8; ++e8) o += b2f(hv[e8]) * SF[512 + bi * 512 + c * 8 + e8];
            }
            int oi = (bq0 + bi) * 256 + t;
            float v = fmaxf(o, 0.f);
            if (F32) ((float*)Out)[oi] = v; else ((short*)Out)[oi] = f2b(v);
        }
        __syncthreads();   // protect A1/STG before next pass
    }
}

// ---------------------------------------------------------------------------
extern "C" void kernel_launch(void* const* d_in, const int* in_sizes, int n_in,
                              void* d_out, int out_size, void* d_ws, size_t ws_size,
                              hipStream_t stream) {
    (void)in_sizes; (void)n_in; (void)out_size; (void)ws_size;
    const void* MIp = d_in[0];
    const void* Qin = d_in[1];
    const void* Cw  = d_in[2];
    const void* Cb  = d_in[3];
    const void* Qw  = d_in[4];
    const void* Qb  = d_in[5];
    const void* Hw  = d_in[6];
    const void* Hb  = d_in[7];
    const void* Uw  = d_in[8];
    const void* Ub  = d_in[9];
    const void* Vw  = d_in[10];
    const void* Vb  = d_in[11];
    const void* Ww  = d_in[12];
    const void* Wb  = d_in[13];
    const void* Jw  = d_in[14];
    const void* Jb  = d_in[15];
    const void* PA  = d_in[16];
    const void* Emb = d_in[17];

    short* jv_ws = (short*)d_ws;   // (S*B, 256) bf16 = 64 MiB

    renet_phase1<<<dim3(2048), dim3(256), 0, stream>>>(MIp, Cw, Cb, Vw, Vb, Jw, PA, jv_ws);
    renet_recur<<<dim3(256), dim3(256), 0, stream>>>(MIp, jv_ws, Qin, Qw, Qb, Uw, Ub,
                                                     Jw, Jb, Ww, Wb, Hw, Hb, PA, Cw, Cb,
                                                     Emb, d_out);
}

// Round 4
// 2564.751 us; speedup vs baseline: 1.3688x; 1.3688x over previous
//
#include <hip/hip_runtime.h>
#include <hip/hip_bf16.h>

// RecurrentEntityNetwork on MI355X. S=128, B=1024, DOBJ=37, QD=11, D=256, M=20.
// Dual-dtype (runtime probe on prelu_a bits): inputs either bf16 or f32.
// phase1: mi = relu(MI@C^T+Cb) -> ws ; jv = relu(mi@V^T+Vb)@J2^T -> ws
// recur : 256 WGs x 512 thr (8 waves, 32-col weight slices => 128 VGPR resident,
//         2 waves/SIMD), 2 batches/WG per pass, 2 passes, 4 barriers/step.

#define S_LEN 128
#define BSZ   1024
#define DOBJ  37
#define QD    11

typedef float f32x4 __attribute__((ext_vector_type(4)));
typedef short bf16x8 __attribute__((ext_vector_type(8)));

#define MFMA16(a, b, c) __builtin_amdgcn_mfma_f32_16x16x32_bf16((a), (b), (c), 0, 0, 0)

__device__ __forceinline__ float b2f(short h) {
    union { unsigned u; float f; } c; c.u = ((unsigned)(unsigned short)h) << 16; return c.f;
}
__device__ __forceinline__ short f2b(float x) {   // f32 -> bf16 RNE
    union { float f; unsigned u; } c; c.f = x;
    return (short)((c.u + 0x7FFFu + ((c.u >> 16) & 1u)) >> 16);
}
__device__ __forceinline__ float ld1(const void* p, int i, bool f32) {
    return f32 ? ((const float*)p)[i] : b2f(((const short*)p)[i]);
}
__device__ __forceinline__ bf16x8 ld8(const void* p, int i, bool f32) {  // i: 8-elem aligned
    if (!f32) return *(const bf16x8*)((const short*)p + i);
    const float* q = (const float*)p + i;
    bf16x8 r;
    #pragma unroll
    for (int e = 0; e < 8; ++e) r[e] = f2b(q[e]);
    return r;
}

// ---------------------------------------------------------------------------
// Phase 1: mi and jv for all (s,b). 64 rows/WG, grid 2048.
// ---------------------------------------------------------------------------
__global__ __launch_bounds__(256, 2) void renet_phase1(
    const void* __restrict__ MI, const void* __restrict__ Cw, const void* __restrict__ Cb,
    const void* __restrict__ Vw, const void* __restrict__ Vb, const void* __restrict__ Jw,
    const void* __restrict__ PA, short* __restrict__ mi_out, short* __restrict__ jv_out)
{
    const bool F32 = (*(const unsigned*)PA == 0x3F800000u);
    __shared__ __align__(16) short A[64 * 264];
    __shared__ __align__(16) float MIL[64 * 40];
    __shared__ float VBL[256];

    const int t = threadIdx.x, r0 = blockIdx.x * 64;
    const int wv = t >> 6, lane = t & 63, lr = lane & 15, quad = lane >> 4;

    VBL[t] = ld1(Vb, t, F32);
    for (int c = 0; c < 10; ++c) {
        int idx = c * 256 + t;
        if (idx < 64 * 37) { int i = idx / 37, k = idx - i * 37; MIL[i * 40 + k] = ld1(MI, (r0 + i) * 37 + k, F32); }
    }
    __syncthreads();

    {   // mi = relu(MI @ Cw^T + Cb), column t; also store to ws
        float cw[DOBJ];
        #pragma unroll
        for (int k = 0; k < DOBJ; ++k) cw[k] = ld1(Cw, t * DOBJ + k, F32);
        float cb = ld1(Cb, t, F32);
        for (int i = 0; i < 64; ++i) {
            float a = cb;
            #pragma unroll
            for (int k = 0; k < DOBJ; ++k) a += MIL[i * 40 + k] * cw[k];
            short h = f2b(fmaxf(a, 0.f));
            A[i * 264 + t] = h;
            mi_out[(r0 + i) * 256 + t] = h;
        }
    }
    __syncthreads();

    const f32x4 Z4 = {0.f, 0.f, 0.f, 0.f};
    f32x4 acc[4][4];

    // v = mi @ Vw^T
    #pragma unroll
    for (int rt = 0; rt < 4; ++rt)
        #pragma unroll
        for (int nt = 0; nt < 4; ++nt) acc[rt][nt] = Z4;
    #pragma unroll
    for (int kt = 0; kt < 8; ++kt) {
        bf16x8 a[4];
        #pragma unroll
        for (int rt = 0; rt < 4; ++rt)
            a[rt] = *(const bf16x8*)&A[(rt * 16 + lr) * 264 + kt * 32 + quad * 8];
        #pragma unroll
        for (int nt = 0; nt < 4; ++nt) {
            int n = wv * 64 + nt * 16 + lr;
            bf16x8 b = ld8(Vw, n * 256 + kt * 32 + quad * 8, F32);
            #pragma unroll
            for (int rt = 0; rt < 4; ++rt) acc[rt][nt] = MFMA16(a[rt], b, acc[rt][nt]);
        }
    }
    __syncthreads();
    #pragma unroll
    for (int nt = 0; nt < 4; ++nt) {
        int n = wv * 64 + nt * 16 + lr;
        float vb = VBL[n];
        #pragma unroll
        for (int rt = 0; rt < 4; ++rt)
            #pragma unroll
            for (int r = 0; r < 4; ++r)
                A[(rt * 16 + quad * 4 + r) * 264 + n] = f2b(fmaxf(acc[rt][nt][r] + vb, 0.f));
    }
    __syncthreads();

    // jv = relu_v @ J2^T (J2 = Jw[:,256:512])
    #pragma unroll
    for (int rt = 0; rt < 4; ++rt)
        #pragma unroll
        for (int nt = 0; nt < 4; ++nt) acc[rt][nt] = Z4;
    #pragma unroll
    for (int kt = 0; kt < 8; ++kt) {
        bf16x8 a[4];
        #pragma unroll
        for (int rt = 0; rt < 4; ++rt)
            a[rt] = *(const bf16x8*)&A[(rt * 16 + lr) * 264 + kt * 32 + quad * 8];
        #pragma unroll
        for (int nt = 0; nt < 4; ++nt) {
            int n = wv * 64 + nt * 16 + lr;
            bf16x8 b = ld8(Jw, n * 768 + 256 + kt * 32 + quad * 8, F32);
            #pragma unroll
            for (int rt = 0; rt < 4; ++rt) acc[rt][nt] = MFMA16(a[rt], b, acc[rt][nt]);
        }
    }
    __syncthreads();
    #pragma unroll
    for (int nt = 0; nt < 4; ++nt) {
        int n = wv * 64 + nt * 16 + lr;
        #pragma unroll
        for (int rt = 0; rt < 4; ++rt)
            #pragma unroll
            for (int r = 0; r < 4; ++r)
                A[(rt * 16 + quad * 4 + r) * 264 + n] = f2b(acc[rt][nt][r]);
    }
    __syncthreads();
    for (int c = 0; c < 16; ++c) {
        int idx = c * 1024 + t * 4;
        int i = idx >> 8, k = idx & 255;
        *(ushort4*)&jv_out[(r0 + i) * 256 + k] = *(const ushort4*)&A[i * 264 + k];
    }
}

// ---------------------------------------------------------------------------
// Recurrence + head. grid 256 x 512 thr. 2 batches/WG per pass, 2 passes.
// LDS 65152 B single block:
//   A1 [60*264] rows 0..39 mem, 40..59 keys; pad col 256-257(f32)=RS,
//                                             260-263(2xf32)=gate logits
//   STG[40*264] relu_u restage + head scratch
//   SJ [ 4*264] rows 0-1 sent(bf16 mi rows), rows 2-3 jv+Jb (bf16)
//   JWL[20*256] key-path J contribution (bf16)
// ---------------------------------------------------------------------------
__global__ __launch_bounds__(512, 2) void renet_recur(
    const short* __restrict__ mi, const short* __restrict__ jv,
    const void* __restrict__ Qin, const void* __restrict__ Qw, const void* __restrict__ Qb,
    const void* __restrict__ Uw, const void* __restrict__ Ub,
    const void* __restrict__ Jw, const void* __restrict__ Jb,
    const void* __restrict__ Ww, const void* __restrict__ Wb,
    const void* __restrict__ Hw, const void* __restrict__ Hb,
    const void* __restrict__ PA, const void* __restrict__ Emb, void* __restrict__ Out)
{
    const bool F32 = (*(const unsigned*)PA == 0x3F800000u);
    __shared__ __align__(16) short LDS[32576];    // 65152 B
    short* const A1  = LDS;            // 60*264 = 15840 shorts
    short* const STG = LDS + 15840;    // 40*264 = 10560
    short* const SJ  = LDS + 26400;    //  4*264 =  1056
    short* const JWL = LDS + 27456;    // 20*256 =  5120  (end 32576)

    const int t = threadIdx.x;                 // 0..511
    const int w8 = t >> 6;                     // wave 0..7
    const int lane = t & 63, lr = lane & 15, quad = lane >> 4;
    const int colb = w8 * 32;                  // this wave's 32-col slice
    const float pa = ld1(PA, 0, F32);
    const f32x4 Z4 = {0.f, 0.f, 0.f, 0.f};
    const int rbase0 = 0, rbase1 = 16, rbase2 = 24;

    float ub[2];
    #pragma unroll
    for (int nt = 0; nt < 2; ++nt) ub[nt] = ld1(Ub, colb + nt * 16 + lr, F32);
    const float bjv = ld1(Jb, t & 255, F32);

    // resident weight fragments: 32-col slices of U and J1 -> 128 VGPRs
    bf16x8 uf[8][2], jf[8][2];
    #pragma unroll
    for (int kt = 0; kt < 8; ++kt)
        #pragma unroll
        for (int nt = 0; nt < 2; ++nt) {
            int nn = colb + nt * 16 + lr;
            uf[kt][nt] = ld8(Uw, nn * 256 + kt * 32 + quad * 8, F32);
            jf[kt][nt] = ld8(Jw, nn * 768 + kt * 32 + quad * 8, F32);
        }

    // keys -> A1 rows 40..59 (pads zeroed)
    for (int c = 0; c < 11; ++c) {
        int idx = c * 512 + t;
        if (idx < 20 * 264) {
            int row = idx / 264, k = idx - row * 264;
            A1[(40 + row) * 264 + k] = (k < 256) ? f2b(ld1(Emb, row * 256 + k, F32)) : (short)0;
        }
    }
    __syncthreads();

    // JWL = relu(Emb@Ww^T+Wb) @ J3^T  (halves split the 20 slots)
    {
        const int col = t & 255, half = t >> 8, m0 = half * 10;
        float* WKS = (float*)STG;
        float wacc[10];
        #pragma unroll
        for (int mm = 0; mm < 10; ++mm) wacc[mm] = 0.f;
        for (int c = 0; c < 32; ++c) {
            bf16x8 wv8 = ld8(Ww, col * 256 + c * 8, F32);
            float wf[8];
            #pragma unroll
            for (int e = 0; e < 8; ++e) wf[e] = b2f(wv8[e]);
            #pragma unroll
            for (int mm = 0; mm < 10; ++mm) {
                bf16x8 e8 = *(const bf16x8*)&A1[(40 + m0 + mm) * 264 + c * 8];
                float s = 0.f;
                #pragma unroll
                for (int e = 0; e < 8; ++e) s += b2f(e8[e]) * wf[e];
                wacc[mm] += s;
            }
        }
        float wb = ld1(Wb, col, F32);
        #pragma unroll
        for (int mm = 0; mm < 10; ++mm) WKS[(m0 + mm) * 256 + col] = fmaxf(wacc[mm] + wb, 0.f);
        __syncthreads();
        float jacc[10];
        #pragma unroll
        for (int mm = 0; mm < 10; ++mm) jacc[mm] = 0.f;
        for (int c = 0; c < 32; ++c) {
            bf16x8 j8 = ld8(Jw, col * 768 + 512 + c * 8, F32);
            float jfv[8];
            #pragma unroll
            for (int e = 0; e < 8; ++e) jfv[e] = b2f(j8[e]);
            #pragma unroll
            for (int mm = 0; mm < 10; ++mm) {
                float4 w0 = *(const float4*)&WKS[(m0 + mm) * 256 + c * 8];
                float4 w1 = *(const float4*)&WKS[(m0 + mm) * 256 + c * 8 + 4];
                jacc[mm] += w0.x * jfv[0] + w0.y * jfv[1] + w0.z * jfv[2] + w0.w * jfv[3]
                          + w1.x * jfv[4] + w1.y * jfv[5] + w1.z * jfv[6] + w1.w * jfv[7];
            }
        }
        __syncthreads();
        #pragma unroll
        for (int mm = 0; mm < 10; ++mm) JWL[(m0 + mm) * 256 + col] = f2b(jacc[mm]);
    }
    __syncthreads();

    for (int p = 0; p < 2; ++p) {
        const int bq0 = blockIdx.x * 4 + p * 2;

        // init mem rows 0..39 from keys (pads zeroed)
        for (int c = 0; c < 21; ++c) {
            int idx = c * 512 + t;
            if (idx < 40 * 264) {
                int row = idx / 264, k = idx - row * 264;
                A1[idx] = (k < 256) ? A1[(40 + row % 20) * 264 + k] : (short)0;
            }
        }
        __syncthreads();

        ushort4 pf_mi = {0, 0, 0, 0};
        short pf_jv;
        // prefetch step 0
        if (t < 128) pf_mi = *(const ushort4*)&mi[(0 * BSZ + bq0 + (t >> 6)) * 256 + (t & 63) * 4];
        pf_jv = jv[(0 * BSZ + bq0 + (t >> 8)) * 256 + (t & 255)];

        for (int s = 0; s < S_LEN; ++s) {
            // ---- stage from prefetched regs
            if (t < 128) *(ushort4*)&SJ[((t >> 6) & 1) * 264 + (t & 63) * 4] = pf_mi;
            SJ[(2 + (t >> 8)) * 264 + (t & 255)] = f2b(b2f(pf_jv) + bjv);
            if (t < 40) *(float*)&A1[t * 264 + 256] = 0.f;     // RS := 0 (pad cols)
            __syncthreads();                                    // B1

            // ---- gate MFMA (waves 0..3): [mem;keys] x sent^T -> pad cols 260-263
            if (w8 < 4) {
                const int gb4[4] = {0, 16, 32, 44};
                const int base = gb4[w8];
                f32x4 ag = Z4;
                #pragma unroll
                for (int kt = 0; kt < 8; ++kt) {
                    bf16x8 a = *(const bf16x8*)&A1[(base + lr) * 264 + kt * 32 + quad * 8];
                    bf16x8 b = *(const bf16x8*)&SJ[lr * 264 + kt * 32 + quad * 8];
                    ag = MFMA16(a, b, ag);
                }
                if (lr < 2) {
                    #pragma unroll
                    for (int r = 0; r < 4; ++r)
                        ((float*)&A1[(base + quad * 4 + r) * 264 + 260])[lr] = ag[r];
                }
            }

            // ---- GEMM1: u = mem @ Uw^T
            f32x4 acc[3][2];
            #pragma unroll
            for (int rt = 0; rt < 3; ++rt)
                #pragma unroll
                for (int nt = 0; nt < 2; ++nt) acc[rt][nt] = Z4;
            #pragma unroll
            for (int kt = 0; kt < 8; ++kt) {
                bf16x8 a0 = *(const bf16x8*)&A1[(rbase0 + lr) * 264 + kt * 32 + quad * 8];
                bf16x8 a1 = *(const bf16x8*)&A1[(rbase1 + lr) * 264 + kt * 32 + quad * 8];
                bf16x8 a2 = *(const bf16x8*)&A1[(rbase2 + lr) * 264 + kt * 32 + quad * 8];
                #pragma unroll
                for (int nt = 0; nt < 2; ++nt) {
                    acc[0][nt] = MFMA16(a0, uf[kt][nt], acc[0][nt]);
                    acc[1][nt] = MFMA16(a1, uf[kt][nt], acc[1][nt]);
                    acc[2][nt] = MFMA16(a2, uf[kt][nt], acc[2][nt]);
                }
            }
            // restage relu(u+Ub) -> STG
            #pragma unroll
            for (int rt = 0; rt < 3; ++rt) {
                int base = (rt == 0) ? rbase0 : (rt == 1) ? rbase1 : rbase2;
                #pragma unroll
                for (int nt = 0; nt < 2; ++nt) {
                    int n = colb + nt * 16 + lr;
                    #pragma unroll
                    for (int r = 0; r < 4; ++r)
                        STG[(base + quad * 4 + r) * 264 + n] = f2b(fmaxf(acc[rt][nt][r] + ub[nt], 0.f));
                }
            }
            // prefetch next step while waiting
            if (s + 1 < S_LEN) {
                if (t < 128) pf_mi = *(const ushort4*)&mi[((s + 1) * BSZ + bq0 + (t >> 6)) * 256 + (t & 63) * 4];
                pf_jv = jv[((s + 1) * BSZ + bq0 + (t >> 8)) * 256 + (t & 255)];
            }
            __syncthreads();                                    // B2

            // ---- GEMM2: jU = relu_u @ J1^T
            f32x4 acc2[3][2];
            #pragma unroll
            for (int rt = 0; rt < 3; ++rt)
                #pragma unroll
                for (int nt = 0; nt < 2; ++nt) acc2[rt][nt] = Z4;
            #pragma unroll
            for (int kt = 0; kt < 8; ++kt) {
                bf16x8 a0 = *(const bf16x8*)&STG[(rbase0 + lr) * 264 + kt * 32 + quad * 8];
                bf16x8 a1 = *(const bf16x8*)&STG[(rbase1 + lr) * 264 + kt * 32 + quad * 8];
                bf16x8 a2 = *(const bf16x8*)&STG[(rbase2 + lr) * 264 + kt * 32 + quad * 8];
                #pragma unroll
                for (int nt = 0; nt < 2; ++nt) {
                    acc2[0][nt] = MFMA16(a0, jf[kt][nt], acc2[0][nt]);
                    acc2[1][nt] = MFMA16(a1, jf[kt][nt], acc2[1][nt]);
                    acc2[2][nt] = MFMA16(a2, jf[kt][nt], acc2[2][nt]);
                }
            }

            // ---- epilogue 1: j -> cand -> upd, sumsq into RS pads
            #pragma unroll
            for (int rt = 0; rt < 3; ++rt) {
                int base = (rt == 0) ? rbase0 : (rt == 1) ? rbase1 : rbase2;
                #pragma unroll
                for (int r = 0; r < 4; ++r) {
                    int row = base + quad * 4 + r;
                    int bi = (row >= 20) ? 1 : 0;
                    int m = row - bi * 20;
                    float gp = ((const float*)&A1[row * 264 + 260])[bi]
                             + ((const float*)&A1[(40 + m) * 264 + 260])[bi];
                    float gate = 1.f / (1.f + __expf(-gp));
                    float ss = 0.f;
                    #pragma unroll
                    for (int nt = 0; nt < 2; ++nt) {
                        int n = colb + nt * 16 + lr;
                        float j = acc2[rt][nt][r] + b2f(SJ[(2 + bi) * 264 + n]) + b2f(JWL[m * 256 + n]);
                        float cand = j > 0.f ? j : pa * j;
                        float u = b2f(A1[row * 264 + n]) + gate * cand;
                        acc2[rt][nt][r] = u;
                        ss += u * u;
                    }
                    ss += __shfl_xor(ss, 1);
                    ss += __shfl_xor(ss, 2);
                    ss += __shfl_xor(ss, 4);
                    ss += __shfl_xor(ss, 8);
                    if (lr == 0 && !(rt == 2 && quad < 2))
                        atomicAdd((float*)&A1[row * 264 + 256], ss);
                }
            }
            __syncthreads();                                    // B3

            // ---- epilogue 2: normalize, write back mem
            #pragma unroll
            for (int rt = 0; rt < 3; ++rt) {
                int base = (rt == 0) ? rbase0 : (rt == 1) ? rbase1 : rbase2;
                #pragma unroll
                for (int r = 0; r < 4; ++r) {
                    int row = base + quad * 4 + r;
                    float sc = 1.f / (sqrtf(*(const float*)&A1[row * 264 + 256]) + 1e-12f);
                    #pragma unroll
                    for (int nt = 0; nt < 2; ++nt) {
                        int n = colb + nt * 16 + lr;
                        A1[row * 264 + n] = f2b(acc2[rt][nt][r] * sc);
                    }
                }
            }
            __syncthreads();                                    // B4
        }

        // ---------------- attention + output head ----------------
        float* SF = (float*)STG;  // QF[0..511] HC[512..1535] EN[1536..1575] AT[1576..1615]
        {
            const int col = t & 255, bi = t >> 8;
            float a = ld1(Qb, col, F32);
            #pragma unroll
            for (int k = 0; k < QD; ++k)
                a += ld1(Qin, (bq0 + bi) * QD + k, F32) * ld1(Qw, col * QD + k, F32);
            SF[bi * 256 + col] = fmaxf(a, 0.f);
        }
        __syncthreads();
        if (t < 40) {
            int bi = t / 20;
            float e = 0.f;
            for (int c = 0; c < 32; ++c) {
                bf16x8 mv = *(const bf16x8*)&A1[t * 264 + c * 8];
                #pragma unroll
                for (int e8 = 0; e8 < 8; ++e8) e += b2f(mv[e8]) * SF[bi * 256 + c * 8 + e8];
            }
            SF[1536 + t] = e;
        }
        __syncthreads();
        if (t < 2) {
            float mx = -1e30f;
            for (int m = 0; m < 20; ++m) mx = fmaxf(mx, SF[1536 + t * 20 + m]);
            float sm = 0.f, ex[20];
            for (int m = 0; m < 20; ++m) { ex[m] = __expf(SF[1536 + t * 20 + m] - mx); sm += ex[m]; }
            float inv = 1.f / sm;
            for (int m = 0; m < 20; ++m) SF[1576 + t * 20 + m] = ex[m] * inv;
        }
        __syncthreads();
        {
            const int col = t & 255, bi = t >> 8;
            float a = 0.f;
            for (int m = 0; m < 20; ++m)
                a += SF[1576 + bi * 20 + m] * b2f(A1[(bi * 20 + m) * 264 + col]);
            SF[512 + bi * 512 + 256 + col] = a;
            SF[512 + bi * 512 + col] = SF[bi * 256 + col];
        }
        __syncthreads();
        {
            const int col = t & 255, bi = t >> 8;
            float o = ld1(Hb, col, F32);
            for (int c = 0; c < 64; ++c) {
                bf16x8 hv = ld8(Hw, col * 512 + c * 8, F32);
                #pragma unroll
                for (int e8 = 0; e8 < 8; ++e8) o += b2f(hv[e8]) * SF[512 + bi * 512 + c * 8 + e8];
            }
            int oi = (bq0 + bi) * 256 + col;
            float v = fmaxf(o, 0.f);
            if (F32) ((float*)Out)[oi] = v; else ((short*)Out)[oi] = f2b(v);
        }
        __syncthreads();   // protect A1/STG before next pass
    }
}

// ---------------------------------------------------------------------------
extern "C" void kernel_launch(void* const* d_in, const int* in_sizes, int n_in,
                              void* d_out, int out_size, void* d_ws, size_t ws_size,
                              hipStream_t stream) {
    (void)in_sizes; (void)n_in; (void)out_size; (void)ws_size;
    const void* MIp = d_in[0];
    const void* Qin = d_in[1];
    const void* Cw  = d_in[2];
    const void* Cb  = d_in[3];
    const void* Qw  = d_in[4];
    const void* Qb  = d_in[5];
    const void* Hw  = d_in[6];
    const void* Hb  = d_in[7];
    const void* Uw  = d_in[8];
    const void* Ub  = d_in[9];
    const void* Vw  = d_in[10];
    const void* Vb  = d_in[11];
    const void* Ww  = d_in[12];
    const void* Wb  = d_in[13];
    const void* Jw  = d_in[14];
    const void* Jb  = d_in[15];
    const void* PA  = d_in[16];
    const void* Emb = d_in[17];

    short* mi_ws = (short*)d_ws;                          // (S*B,256) bf16 = 64 MiB
    short* jv_ws = mi_ws + (size_t)S_LEN * BSZ * 256;     // (S*B,256) bf16 = 64 MiB

    renet_phase1<<<dim3(2048), dim3(256), 0, stream>>>(MIp, Cw, Cb, Vw, Vb, Jw, PA, mi_ws, jv_ws);
    renet_recur<<<dim3(256), dim3(512), 0, stream>>>(mi_ws, jv_ws, Qin, Qw, Qb, Uw, Ub,
                                                     Jw, Jb, Ww, Wb, Hw, Hb, PA, Emb, d_out);
}